// Round 2
// baseline (15091.266 us; speedup 1.0000x reference)
//
#include <hip/hip_runtime.h>
#include <cstdint>
#include <cstddef>

// ============================================================================
// QuantGRU on MI355X — round 4
//
// vs round 3 (failed, no counters — presumed hang in the un-hardened
// sc0-only exchange or mis-grouped XCD election):
//  * Dual-published exchange slots: writer stores {tag,value} to slot A
//    with sc0 (L2-local fast path) AND to mirror slot B with sc1
//    (agent-coherent — byte-identical mechanism to round 2's PROVEN
//    __hip_atomic AGENT path).  Pollers spin on A, probe B every 4th
//    iteration.  Progress is guaranteed regardless of sc0/sc1 semantics
//    or election correctness; tag-match gating makes staleness harmless.
//  * XCC_ID read via __builtin_amdgcn_s_getreg(63508) (numeric hwreg
//    encoding: id=20 HW_REG_XCC_ID, offset 0, size 32) — no asm symbol
//    name risk.  Election uses only device-scope atomics.
//  * Early-clobber asm outputs.  Numeric path byte-identical to round 2
//    (absmax margin is thin: expected exactly 0.06115723).
// ============================================================================

typedef int   v4i __attribute__((ext_vector_type(4)));
typedef float v4f __attribute__((ext_vector_type(4)));

#define T_STEPS 1024
#define OUT_MAIN_FLOATS (1024*64*256)          // 16,777,216
#define WXQ_DOUT_OFF 16842752                  // out_bytes(67,174,400) - 50,331,648

__device__ __forceinline__ float clamp128(float x) {
  return fminf(fmaxf(x, -128.0f), 127.0f);
}
__device__ __forceinline__ int permj(int j) {           // haste row -> pt row
  return j < 256 ? j + 256 : (j < 512 ? j - 256 : j);
}
__device__ __forceinline__ float sigmoidf_(float x) {
  return __fdividef(1.0f, 1.0f + __expf(-x));
}
__device__ __forceinline__ float tanhf_(float x) {
  float e = __expf(-2.0f * fabsf(x));
  float t = __fdividef(1.0f - e, 1.0f + e);
  return copysignf(t, x);
}
// monotone uint key for signed float max
__device__ __forceinline__ unsigned skey(float x) {
  unsigned u = __float_as_uint(x);
  return (u & 0x80000000u) ? ~u : (u | 0x80000000u);
}
__device__ __forceinline__ float sdec(unsigned k) {
  unsigned u = (k & 0x80000000u) ? (k ^ 0x80000000u) : ~k;
  return __uint_as_float(u);
}
__device__ __forceinline__ float wave_amax(float v) {
  #pragma unroll
  for (int m = 1; m <= 32; m <<= 1) v = fmaxf(v, __shfl_xor(v, m, 64));
  return v;
}

// ---- exchange slot accessors -----------------------------------------------
// A path: sc0 (bypass L1, L2-resident) — fast when peers share an XCD L2.
// B path: sc1 (agent-coherent via memory-side fabric) — the round-2-proven
// always-correct path.  Writers publish both; pollers consume whichever
// shows the current tag first.
__device__ __forceinline__ void st_ab_u64(unsigned long long* pa,
                                          unsigned long long* pb,
                                          unsigned long long v) {
  asm volatile("global_store_dwordx2 %0, %2, off sc0\n\t"
               "global_store_dwordx2 %1, %2, off sc1"
               :: "v"(pa), "v"(pb), "v"(v) : "memory");
}
__device__ __forceinline__ unsigned long long ld_a_u64(
    const unsigned long long* p) {
  unsigned long long v;
  asm volatile("global_load_dwordx2 %0, %1, off sc0\n\ts_waitcnt vmcnt(0)"
               : "=&v"(v) : "v"(p) : "memory");
  return v;
}
__device__ __forceinline__ unsigned long long ld_b_u64(
    const unsigned long long* p) {
  unsigned long long v;
  asm volatile("global_load_dwordx2 %0, %1, off sc1\n\ts_waitcnt vmcnt(0)"
               : "=&v"(v) : "v"(p) : "memory");
  return v;
}

#define MFMA_I8(a, b, c) __builtin_amdgcn_mfma_i32_16x16x64_i8(a, b, c, 0, 0, 0)

// ---------------- absmax over a float tensor (n4 = n/4) ----------------
__global__ void k_absmax(const float* __restrict__ p, int n4, unsigned* slot) {
  int i = blockIdx.x * blockDim.x + threadIdx.x;
  int stride = gridDim.x * blockDim.x;
  const v4f* p4 = (const v4f*)p;
  float m = 0.0f;
  for (; i < n4; i += stride) {
    v4f v = p4[i];
    m = fmaxf(m, fmaxf(fmaxf(fabsf(v[0]), fabsf(v[1])),
                       fmaxf(fabsf(v[2]), fabsf(v[3]))));
  }
  m = wave_amax(m);
  if ((threadIdx.x & 63) == 0) atomicMax(slot, __float_as_uint(m));
}

// ---------------- 768x256 weight -> int8 MFMA B-fragments ----------------
__global__ void k_frag(const float* __restrict__ src,
                       const unsigned* __restrict__ slots, int slot_idx,
                       signed char* __restrict__ dst) {
  int id = blockIdx.x * 256 + threadIdx.x;   // 0..49151
  float s = fmaxf(__uint_as_float(slots[slot_idx]) / 127.0f, 1e-8f);
  int bq   = id & 3;
  int lane = (id >> 2) & 63;
  int kc   = (id >> 8) & 3;
  int ct   = id >> 10;
  int n = ct * 16 + (lane & 15);
  int k = kc * 64 + (lane >> 4) * 16 + bq * 4;
  const float* p = src + permj(n) * 256 + k;
  int b0 = ((int)clamp128(rintf(p[0] / s))) & 255;
  int b1 = ((int)clamp128(rintf(p[1] / s))) & 255;
  int b2 = ((int)clamp128(rintf(p[2] / s))) & 255;
  int b3 = ((int)clamp128(rintf(p[3] / s))) & 255;
  ((int*)dst)[id] = b0 | (b1 << 8) | (b2 << 16) | (b3 << 24);
}

// ---------------- biases: reorder + fake-quant (dequantized fp32) ----------
__global__ void k_bias(const float* __restrict__ bih, const float* __restrict__ bhh,
                       const unsigned* __restrict__ slots, float* __restrict__ bqo) {
  int j = threadIdx.x;               // 0..767
  float s_bx = fmaxf(__uint_as_float(slots[3]) / 127.0f, 1e-8f);
  float s_br = fmaxf(__uint_as_float(slots[4]) / 127.0f, 1e-8f);
  int pr = permj(j);
  bqo[j]       = s_bx * clamp128(rintf(bih[pr] / s_bx));
  bqo[768 + j] = s_br * clamp128(rintf(bhh[pr] / s_br));
}

// ---------------- quantize x -> int8 ----------------
__global__ void k_xq(const float* __restrict__ x, const unsigned* __restrict__ slots,
                     signed char* __restrict__ xq8, int n4) {
  int i = blockIdx.x * blockDim.x + threadIdx.x;
  if (i >= n4) return;
  float s_x = fmaxf(__uint_as_float(slots[0]) / 127.0f, 1e-8f);
  v4f v = ((const v4f*)x)[i];
  int b0 = ((int)clamp128(rintf(v[0] / s_x))) & 255;
  int b1 = ((int)clamp128(rintf(v[1] / s_x))) & 255;
  int b2 = ((int)clamp128(rintf(v[2] / s_x))) & 255;
  int b3 = ((int)clamp128(rintf(v[3] / s_x))) & 255;
  ((int*)xq8)[i] = b0 | (b1 << 8) | (b2 << 16) | (b3 << 24);
}

// ---------------- Wx GEMM, int8 MFMA (both passes) ----------------
__global__ __launch_bounds__(1024) void k_wx_i8(
    const signed char* __restrict__ xq8, const signed char* __restrict__ wf,
    unsigned* __restrict__ slots, signed char* __restrict__ wxq, int mode) {
  const int t = blockIdx.x;
  const int tid = threadIdx.x, lane = tid & 63, w = tid >> 6;
  const int cl = lane & 15, lh = lane >> 4;

  v4i Bz[4], Br[4], Bn[4];
  #pragma unroll
  for (int kc = 0; kc < 4; ++kc) {
    Bz[kc] = *(const v4i*)(wf + (((w)*4      + kc) * 64 + lane) * 16);
    Br[kc] = *(const v4i*)(wf + (((w + 16)*4 + kc) * 64 + lane) * 16);
    Bn[kc] = *(const v4i*)(wf + (((w + 32)*4 + kc) * 64 + lane) * 16);
  }
  v4i acc[3][4];
  #pragma unroll
  for (int p = 0; p < 3; ++p)
    #pragma unroll
    for (int rt = 0; rt < 4; ++rt) acc[p][rt] = (v4i){0, 0, 0, 0};

  const signed char* xr = xq8 + t * 16384;
  #pragma unroll
  for (int kc = 0; kc < 4; ++kc)
    #pragma unroll
    for (int rt = 0; rt < 4; ++rt) {
      v4i A = *(const v4i*)(xr + (rt * 16 + cl) * 256 + kc * 64 + lh * 16);
      acc[0][rt] = MFMA_I8(A, Bz[kc], acc[0][rt]);
      acc[1][rt] = MFMA_I8(A, Br[kc], acc[1][rt]);
      acc[2][rt] = MFMA_I8(A, Bn[kc], acc[2][rt]);
    }

  if (mode == 0) {
    int mm = 0;
    #pragma unroll
    for (int p = 0; p < 3; ++p)
      #pragma unroll
      for (int rt = 0; rt < 4; ++rt)
        #pragma unroll
        for (int rg = 0; rg < 4; ++rg) mm = max(mm, abs(acc[p][rt][rg]));
    #pragma unroll
    for (int m = 1; m <= 32; m <<= 1) mm = max(mm, __shfl_xor(mm, m, 64));
    if (lane == 0) atomicMax((int*)(slots + 5), mm);
  } else {
    int islot = *(const int*)(slots + 5);
    float maxMf = (float)islot;
    float s_x = fmaxf(__uint_as_float(slots[0]) / 127.0f, 1e-8f);
    float s_W = fmaxf(__uint_as_float(slots[1]) / 127.0f, 1e-8f);
    float s_xW = s_x * s_W;
    float s_wx = fmaxf(s_xW * maxMf / 127.0f, 1e-8f);
    #pragma unroll
    for (int p = 0; p < 3; ++p)
      #pragma unroll
      for (int rt = 0; rt < 4; ++rt) {
        int dw = 0;
        #pragma unroll
        for (int rg = 0; rg < 4; ++rg) {
          float qf = clamp128(rintf((s_xW * (float)acc[p][rt][rg]) / s_wx));
          dw |= (((int)qf) & 255) << (rg * 8);
        }
        ((int*)wxq)[t * 12288 + p * 4096 + rt * 1024 + w * 64 + lh * 16 + cl] = dw;
      }
  }
}

// ---------------- cross-WG max exchange, self-tagged dual-slot protocol ----
// Slot = aligned 8B {tag:hi32, value:lo32}; one per (parity, wg, channel),
// mirrored in A (sc0/L2-local) and B (sc1/agent-coherent) arrays.
// Writers (wave0 lanes 0..NCH-1): one sc0 store to A + one sc1 store to B.
// Pollers (wave1, one per remote-wg x channel): spin sc0 loads on A,
// probe B with an sc1 load every 4th iteration; on exact tag match,
// ds_atomic_max value into the LDS result set.  The B path is identical
// to the round-2-proven agent-scope protocol => progress guaranteed even
// if sc0 semantics or the XCD election are wrong.  Parity double-buffer +
// monotone tags: a slot is only overwritten two rounds later, which
// requires all peers published round r+1, ordered after they consumed
// round r (second barrier).  No ABA; stale reads can't match the tag.
template <int NCH>
__device__ __forceinline__ void xchg(unsigned* keys, unsigned tag,
    unsigned (*lred)[8], unsigned long long* gslotA, unsigned long long* gslotB,
    int wg, int tid, int lane) {
  const int rset = tag % 3;
  #pragma unroll
  for (int c = 0; c < NCH; ++c) {
    unsigned v = keys[c];
    #pragma unroll
    for (int m = 1; m <= 32; m <<= 1)
      v = max(v, (unsigned)__shfl_xor((int)v, m, 64));
    keys[c] = v;
  }
  if (lane == 0) {
    #pragma unroll
    for (int c = 0; c < NCH; ++c) atomicMax(&lred[rset][c], keys[c]);
  }
  __syncthreads();
  const int par = tag & 1;
  if (tid < NCH) {
    unsigned long long v =
        ((unsigned long long)tag << 32) | (unsigned long long)lred[rset][tid];
    int si = (par * 4 + wg) * 8 + tid;
    st_ab_u64(&gslotA[si], &gslotB[si], v);
  } else if (tid == 32) {
    int ns = rset + 1; if (ns == 3) ns = 0;       // pre-zero next ring set
    #pragma unroll
    for (int c = 0; c < 8; ++c) lred[ns][c] = 0u;
  } else if (tid >= 64 && tid < 64 + 3 * NCH) {
    int idx = tid - 64;
    int owi = idx / NCH;
    int c = idx - owi * NCH;
    int ow = owi + (owi >= wg ? 1 : 0);
    int si = (par * 4 + ow) * 8 + c;
    unsigned long long* pa = &gslotA[si];
    unsigned long long* pb = &gslotB[si];
    unsigned long long v;
    int it = 0;
    for (;;) {
      v = ld_a_u64(pa);
      if ((unsigned)(v >> 32) == tag) break;
      if ((it++ & 3) == 3) {
        v = ld_b_u64(pb);
        if ((unsigned)(v >> 32) == tag) break;
      }
    }
    atomicMax(&lred[rset][c], (unsigned)v);
  }
  __syncthreads();
  #pragma unroll
  for (int c = 0; c < NCH; ++c) keys[c] = lred[rset][c];
}

// ---------------- the recurrence: 4 workgroups, 16 batch rows each ---------
// Launched with grid=256; workers elected onto one XCD, losers exit.
__global__ __launch_bounds__(1024) void k_recur4b(
    const signed char* __restrict__ wxq, const signed char* __restrict__ brf,
    const float* __restrict__ bq, const unsigned* __restrict__ slots,
    const float* __restrict__ h0p, float* __restrict__ out,
    unsigned long long* __restrict__ gslotA,
    unsigned long long* __restrict__ gslotB, int* ectl) {
  __shared__ signed char ah[16 * 272];     // int8 h rows (WG-local), pad stride
  __shared__ unsigned lred[3][8];          // 3-set ring x 8 channels
  __shared__ int s_role;

  const int tid = threadIdx.x;

  // ---- same-XCD election: ectl[0..7] per-XCD claim counters, ectl[8]
  // winner word (0 = undecided, else xcc+1).  First XCD to accumulate 4
  // claims wins; its first 4 claimers take roles 0..3.  Device-scope
  // atomics only (proven coherent); 256 WGs / 8 XCDs guarantees some
  // XCD reaches 4 claims => the winner word is always set => no deadlock.
  // Even if XCC_ID were misread, the B-slot path keeps the exchange
  // correct (slower), so election quality is perf-only.
  if (tid == 0) {
    // hwreg(HW_REG_XCC_ID=20, offset=0, size=32) -> 20 | (31<<11) = 63508
    unsigned xcc = ((unsigned)__builtin_amdgcn_s_getreg(63508)) & 7u;
    int role = -1;
    int claim = atomicAdd(&ectl[xcc], 1);
    if (claim < 4) {
      if (claim == 3) atomicCAS(&ectl[8], 0, (int)xcc + 1);
      int wv;
      do {
        wv = __hip_atomic_load(&ectl[8], __ATOMIC_RELAXED,
                               __HIP_MEMORY_SCOPE_AGENT);
      } while (wv == 0);
      if (wv == (int)xcc + 1) role = claim;
    }
    s_role = role;
  }
  __syncthreads();
  if (s_role < 0) return;
  const int wg = s_role;                   // 0..3 -> batch rows 16*wg..+15

  const int lane = tid & 63;
  const int w = tid >> 6;                  // 16 waves: col tiles {w, w+16, w+32}
  const int cl = lane & 15;
  const int lh = lane >> 4;
  const int j = w * 16 + cl;               // h column 0..255
  const int brow = wg * 16 + lh * 4;       // +rg = global batch row

  if (tid < 24) ((unsigned*)lred)[tid] = 0u;

  float s_x = fmaxf(__uint_as_float(slots[0]) / 127.0f, 1e-8f);
  float s_W = fmaxf(__uint_as_float(slots[1]) / 127.0f, 1e-8f);
  float s_R = fmaxf(__uint_as_float(slots[2]) / 127.0f, 1e-8f);
  float maxM0 = (float)(*(const int*)(slots + 5));
  float s_wx = fmaxf(s_x * s_W * maxM0 / 127.0f, 1e-8f);

  float bxz = bq[j], bxr = bq[j + 256], bxn = bq[j + 512];
  float brz = bq[768 + j], brr = bq[1024 + j], brn = bq[1280 + j];

  v4i Bz[4], Br[4], Bn[4];                 // R fragments, resident
  #pragma unroll
  for (int kc = 0; kc < 4; ++kc) {
    Bz[kc] = *(const v4i*)(brf + (((w)*4      + kc) * 64 + lane) * 16);
    Br[kc] = *(const v4i*)(brf + (((w + 16)*4 + kc) * 64 + lane) * 16);
    Bn[kc] = *(const v4i*)(brf + (((w + 32)*4 + kc) * 64 + lane) * 16);
  }

  float h[4];
  #pragma unroll
  for (int rg = 0; rg < 4; ++rg) h[rg] = h0p[(brow + rg) * 256 + j];

  __syncthreads();                         // lred zero visible

  unsigned tag = 1;
  float sh;
  {
    float m = fmaxf(fmaxf(fabsf(h[0]), fabsf(h[1])),
                    fmaxf(fabsf(h[2]), fabsf(h[3])));
    unsigned kk[1] = {__float_as_uint(m)};
    xchg<1>(kk, tag++, lred, gslotA, gslotB, wg, tid, lane);
    sh = fmaxf(__uint_as_float(kk[0]) / 127.0f, 1e-8f);
    float ish = 1.0f / sh;
    #pragma unroll
    for (int rg = 0; rg < 4; ++rg)
      ah[(lh * 4 + rg) * 272 + j] = (signed char)(int)rintf(h[rg] * ish);
    __syncthreads();
  }

  for (int t = 0; t < T_STEPS; ++t) {
    // Wx bytes for this step (coalesced dwords)
    const signed char* wb = wxq + (size_t)t * 49152 + (wg << 12) + (tid << 2);
    int wvz = *(const int*)(wb);
    int wvr = *(const int*)(wb + 16384);
    int wvn = *(const int*)(wb + 32768);

    // ---- GEMM: 16x768 = ah(16x256,i8) @ R(256x768,i8), exact ----
    v4i az4 = {0,0,0,0}, ar4 = {0,0,0,0}, an4 = {0,0,0,0};
    #pragma unroll
    for (int kc = 0; kc < 4; ++kc) {
      v4i A = *(const v4i*)(ah + cl * 272 + kc * 64 + lh * 16);
      az4 = MFMA_I8(A, Bz[kc], az4);
      ar4 = MFMA_I8(A, Br[kc], ar4);
      an4 = MFMA_I8(A, Bn[kc], an4);
    }

    // ---- R1: global max|acc| ----
    int mm = 0;
    #pragma unroll
    for (int rg = 0; rg < 4; ++rg)
      mm = max(mm, max(abs(az4[rg]), max(abs(ar4[rg]), abs(an4[rg]))));
    unsigned kk[5];
    kk[0] = (unsigned)mm;
    xchg<1>(kk, tag++, lred, gslotA, gslotB, wg, tid, lane);
    float maxMf = (float)(int)kk[0];
    float s_Rh = fmaxf(sh * s_R * maxMf / 127.0f, 1e-8f);
    float fRh = (sh * s_R) / s_Rh;

    // ---- stage B: z_pre, r_pre, Rh_n+br_n + abs/signed maxes ----
    float zp[4], rp[4], nb[4];
    float az = 0.0f, ar = 0.0f, an = 0.0f;
    float mzs = -3.402823466e38f, mrs = -3.402823466e38f;
    #pragma unroll
    for (int rg = 0; rg < 4; ++rg) {
      float Rz = s_Rh * rintf((float)az4[rg] * fRh);
      float Rr = s_Rh * rintf((float)ar4[rg] * fRh);
      float Rn = s_Rh * rintf((float)an4[rg] * fRh);
      float wz = s_wx * (float)((signed char)(wvz >> (rg * 8)));
      float wr = s_wx * (float)((signed char)(wvr >> (rg * 8)));
      float a1 = ((wz + bxz) + Rz) + brz;
      float a2 = ((wr + bxr) + Rr) + brr;
      float a3 = Rn + brn;
      zp[rg] = a1; rp[rg] = a2; nb[rg] = a3;
      az = fmaxf(az, fabsf(a1)); ar = fmaxf(ar, fabsf(a2));
      an = fmaxf(an, fabsf(a3));
      mzs = fmaxf(mzs, a1); mrs = fmaxf(mrs, a2);
    }
    kk[0] = __float_as_uint(az); kk[1] = __float_as_uint(ar);
    kk[2] = __float_as_uint(an); kk[3] = skey(mzs); kk[4] = skey(mrs);
    xchg<5>(kk, tag++, lred, gslotA, gslotB, wg, tid, lane);
    float s1 = fmaxf(__uint_as_float(kk[0]) / 127.0f, 1e-8f), i1 = 1.0f / s1;
    float s2 = fmaxf(__uint_as_float(kk[1]) / 127.0f, 1e-8f), i2 = 1.0f / s2;
    float s3 = fmaxf(__uint_as_float(kk[2]) / 127.0f, 1e-8f), i3 = 1.0f / s3;
    float zq_max = s1 * rintf(sdec(kk[3]) * i1);
    float rq_max = s2 * rintf(sdec(kk[4]) * i2);
    float s4 = fmaxf(sigmoidf_(zq_max) / 127.0f, 1e-8f), i4 = 1.0f / s4;
    float s5 = fmaxf(sigmoidf_(rq_max) / 127.0f, 1e-8f), i5 = 1.0f / s5;

    // ---- stage C: z final, rRh ----
    float zf[4], rr_[4];
    float m6 = 0.0f;
    #pragma unroll
    for (int rg = 0; rg < 4; ++rg) {
      float zq = s1 * rintf(zp[rg] * i1);
      float rq = s2 * rintf(rp[rg] * i2);
      float zv = sigmoidf_(zq);
      float rv = sigmoidf_(rq);
      zf[rg] = s4 * rintf(zv * i4);
      float rq2 = s5 * rintf(rv * i5);
      float nbq = s3 * rintf(nb[rg] * i3);
      float rr = rq2 * nbq;
      rr_[rg] = rr;
      m6 = fmaxf(m6, fabsf(rr));
    }
    kk[0] = __float_as_uint(m6);
    xchg<1>(kk, tag++, lred, gslotA, gslotB, wg, tid, lane);
    float s6 = fmaxf(__uint_as_float(kk[0]) / 127.0f, 1e-8f), i6 = 1.0f / s6;

    // ---- stage D: g_pre ----
    float gp[4];
    float m7 = 0.0f;
    #pragma unroll
    for (int rg = 0; rg < 4; ++rg) {
      float rrq = s6 * rintf(rr_[rg] * i6);
      float wn = s_wx * (float)((signed char)(wvn >> (rg * 8)));
      float g = (wn + bxn) + rrq;
      gp[rg] = g;
      m7 = fmaxf(m7, fabsf(g));
    }
    kk[0] = __float_as_uint(m7);
    xchg<1>(kk, tag++, lred, gslotA, gslotB, wg, tid, lane);
    float m7g = __uint_as_float(kk[0]);
    float s7 = fmaxf(m7g / 127.0f, 1e-8f), i7 = 1.0f / s7;
    float gq_max = s7 * rintf(m7g * i7);
    float s8 = fmaxf(tanhf_(gq_max) / 127.0f, 1e-8f), i8v = 1.0f / s8;

    // ---- stage E: g, old/new contribs ----
    float ov[4], nv[4];
    float mo = 0.0f, mn = 0.0f;
    #pragma unroll
    for (int rg = 0; rg < 4; ++rg) {
      float gpq = s7 * rintf(gp[rg] * i7);
      float gv = tanhf_(gpq);
      float gq = s8 * rintf(gv * i8v);
      float o = zf[rg] * h[rg];
      float n = (1.0f - zf[rg]) * gq;
      ov[rg] = o; nv[rg] = n;
      mo = fmaxf(mo, fabsf(o)); mn = fmaxf(mn, fabsf(n));
    }
    kk[0] = __float_as_uint(mo); kk[1] = __float_as_uint(mn);
    xchg<2>(kk, tag++, lred, gslotA, gslotB, wg, tid, lane);
    float s9  = fmaxf(__uint_as_float(kk[0]) / 127.0f, 1e-8f), i9  = 1.0f / s9;
    float s10 = fmaxf(__uint_as_float(kk[1]) / 127.0f, 1e-8f), i10 = 1.0f / s10;

    // ---- stage F: h_new, write output ----
    float mh = 0.0f;
    #pragma unroll
    for (int rg = 0; rg < 4; ++rg) {
      float oq = s9  * rintf(ov[rg] * i9);
      float nq = s10 * rintf(nv[rg] * i10);
      float hn = oq + nq;
      h[rg] = hn;
      mh = fmaxf(mh, fabsf(hn));
      out[t * 16384 + (brow + rg) * 256 + j] = hn;
    }
    kk[0] = __float_as_uint(mh);
    xchg<1>(kk, tag++, lred, gslotA, gslotB, wg, tid, lane);
    sh = fmaxf(__uint_as_float(kk[0]) / 127.0f, 1e-8f);
    float ish = 1.0f / sh;
    #pragma unroll
    for (int rg = 0; rg < 4; ++rg)
      ah[(lh * 4 + rg) * 272 + j] = (signed char)(int)rintf(h[rg] * ish);
    __syncthreads();                       // ah ready for next step (block-local)
  }

  // h_last
  #pragma unroll
  for (int rg = 0; rg < 4; ++rg)
    out[OUT_MAIN_FLOATS + (brow + rg) * 256 + j] = h[rg];
}

// ============================================================================
extern "C" void kernel_launch(void* const* d_in, const int* in_sizes, int n_in,
                              void* d_out, int out_size, void* d_ws, size_t ws_size,
                              hipStream_t stream) {
  const float* x   = (const float*)d_in[0];   // (1024,64,256)
  const float* wih = (const float*)d_in[1];   // (768,256)
  const float* whh = (const float*)d_in[2];   // (768,256)
  const float* bih = (const float*)d_in[3];   // (768,)
  const float* bhh = (const float*)d_in[4];   // (768,)
  const float* h0  = (const float*)d_in[5];   // (64,256)
  float* out = (float*)d_out;

  // d_ws layout: [0..255] absmax slots, [512..1023] tagged A-slots
  // (2 parity x 4 wg x 8 ch x 8B, sc0/L2-local), [1024..1059] election
  // ctrl (8 XCD counters + winner word), [2048..2559] tagged B-slots
  // (agent-coherent mirror), [4096..] bq, [10240..] fragment buffer F.
  unsigned* slots = (unsigned*)d_ws;
  unsigned long long* gslotA = (unsigned long long*)((char*)d_ws + 512);
  int* ectl       = (int*)((char*)d_ws + 1024);
  unsigned long long* gslotB = (unsigned long long*)((char*)d_ws + 2048);
  float* bq       = (float*)((char*)d_ws + 4096);
  signed char* F  = (signed char*)d_ws + 10240;          // 196,608 B

  signed char* wxq = (signed char*)d_out + WXQ_DOUT_OFF; // tail of d_out
  signed char* xq8 = (signed char*)d_out;                // head (dead later)

  hipMemsetAsync(d_ws, 0, 4096, stream);

  k_absmax<<<dim3(1024), dim3(256), 0, stream>>>(x,   16777216 / 4, slots + 0);
  k_absmax<<<dim3(96),   dim3(256), 0, stream>>>(wih, 196608 / 4,   slots + 1);
  k_absmax<<<dim3(96),   dim3(256), 0, stream>>>(whh, 196608 / 4,   slots + 2);
  k_absmax<<<dim3(1),    dim3(256), 0, stream>>>(bih, 768 / 4,      slots + 3);
  k_absmax<<<dim3(1),    dim3(256), 0, stream>>>(bhh, 768 / 4,      slots + 4);

  k_frag<<<dim3(192), dim3(256), 0, stream>>>(wih, slots, 1, F);   // W frags
  k_bias<<<dim3(1), dim3(768), 0, stream>>>(bih, bhh, slots, bq);
  k_xq<<<dim3(16384), dim3(256), 0, stream>>>(x, slots, xq8, 4194304);

  k_wx_i8<<<dim3(1024), dim3(1024), 0, stream>>>(xq8, F, slots, wxq, 0);
  k_wx_i8<<<dim3(1024), dim3(1024), 0, stream>>>(xq8, F, slots, wxq, 1);

  k_frag<<<dim3(192), dim3(256), 0, stream>>>(whh, slots, 2, F);   // R frags

  k_recur4b<<<dim3(256), dim3(1024), 0, stream>>>(wxq, F, bq, slots, h0, out,
                                                  gslotA, gslotB, ectl);
}